// Round 1
// baseline (129.933 us; speedup 1.0000x reference)
//
#include <hip/hip_runtime.h>
#include <hip/hip_bf16.h>
#include <stdint.h>

#define BATCH 8192
#define IN    1024
#define OUTD  1024
#define PBASIS 8

typedef __attribute__((ext_vector_type(8))) short bf16x8;
typedef __attribute__((ext_vector_type(4))) float floatx4;

__device__ __forceinline__ unsigned short f2bf(float f) {
    union { float f; unsigned u; } v; v.f = f;
    unsigned u = v.u;
    u += 0x7fffu + ((u >> 16) & 1u);   // RNE; inputs are finite randn, no NaN path needed
    return (unsigned short)(u >> 16);
}

// w_eff[o,i] = bf16( (sum_p coef[o,i,p]) * weights[o,i] ); 2 elements/thread
__global__ void weff_kernel(const float* __restrict__ coef,
                            const float* __restrict__ w,
                            unsigned short* __restrict__ weff) {
    int idx = blockIdx.x * blockDim.x + threadIdx.x;   // covers elements 2*idx, 2*idx+1
    size_t e0 = (size_t)idx * 2;
    const float4* c4 = (const float4*)(coef + e0 * PBASIS);
    float4 a = c4[0], b = c4[1], c = c4[2], d = c4[3];
    float s0 = (a.x + a.y + a.z + a.w) + (b.x + b.y + b.z + b.w);
    float s1 = (c.x + c.y + c.z + c.w) + (d.x + d.y + d.z + d.w);
    float2 ww = ((const float2*)w)[idx];
    unsigned b0 = f2bf(s0 * ww.x);
    unsigned b1 = f2bf(s1 * ww.y);
    ((unsigned*)weff)[idx] = b0 | (b1 << 16);
}

// x (f32) -> bf16, 8 elements/thread (two float4 reads, one 16B store)
__global__ void cvtx_kernel(const float* __restrict__ x, unsigned short* __restrict__ xb) {
    int idx = blockIdx.x * blockDim.x + threadIdx.x;
    const float4* p = (const float4*)(x + (size_t)idx * 8);
    float4 a = p[0], b = p[1];
    uint4 o;
    o.x = (unsigned)f2bf(a.x) | ((unsigned)f2bf(a.y) << 16);
    o.y = (unsigned)f2bf(a.z) | ((unsigned)f2bf(a.w) << 16);
    o.z = (unsigned)f2bf(b.x) | ((unsigned)f2bf(b.y) << 16);
    o.w = (unsigned)f2bf(b.z) | ((unsigned)f2bf(b.w) << 16);
    ((uint4*)xb)[idx] = o;
}

// C[m,n] = sum_k A[m,k] * B[n,k]; A=[8192,1024] bf16, B=[1024,1024] bf16, C f32.
// m97 structure: 128x128 tile, BK=32, 4 waves in 2x2, each wave 4x4 of 16x16x32 MFMA.
__global__ __launch_bounds__(256, 2) void gemm_bt(
        const unsigned short* __restrict__ A,
        const unsigned short* __restrict__ B,
        float* __restrict__ C) {
    constexpr int K = IN, BM = 128, BN = 128, BK = 32;
    __shared__ unsigned short As[BM * BK];   // 8 KB
    __shared__ unsigned short Bs[BN * BK];   // 8 KB

    const int tid  = threadIdx.x;
    const int bm   = blockIdx.x, bn = blockIdx.y;
    const int lane = tid & 63;
    const int wave = tid >> 6;
    const int wm   = wave & 1, wn = wave >> 1;   // 2x2 wave grid
    const int t    = lane & 15;                  // row-within-16 (M/N index)
    const int q    = lane >> 4;                  // quad (K-chunk index)
    const int sw   = (t >> 1) & 3;               // XOR swizzle of 16B chunk

    // Staging: linear 16B chunk L = j*256 + tid; row = L>>2, lds chunk = L&3.
    // Global source chunk is XOR-swizzled so LDS stays strictly lane-contiguous
    // (global_load_lds requirement) while fragment reads become ~conflict-free.
    const char* gA[2]; const char* gB[2];
    void* lA[2]; void* lB[2];
#pragma unroll
    for (int j = 0; j < 2; ++j) {
        int L = j * 256 + tid;
        int row = L >> 2;
        int cg  = (L & 3) ^ ((row >> 1) & 3);
        gA[j] = (const char*)(A + ((size_t)(bm * BM + row)) * K + cg * 8);
        gB[j] = (const char*)(B + ((size_t)(bn * BN + row)) * K + cg * 8);
        lA[j] = (void*)(As + (size_t)L * 8);
        lB[j] = (void*)(Bs + (size_t)L * 8);
    }

    // Hoisted fragment LDS pointers. A frag: A[m=t][k=q*8+j]; B frag: B[n=t][k=q*8+j].
    const bf16x8* aptr[4]; const bf16x8* bptr[4];
#pragma unroll
    for (int i = 0; i < 4; ++i) {
        int rowa = wm * 64 + i * 16 + t;
        int rowb = wn * 64 + i * 16 + t;
        aptr[i] = (const bf16x8*)(As + rowa * BK + ((q ^ sw) * 8));
        bptr[i] = (const bf16x8*)(Bs + rowb * BK + ((q ^ sw) * 8));
    }

    floatx4 acc[4][4];
#pragma unroll
    for (int i = 0; i < 4; ++i)
#pragma unroll
        for (int j = 0; j < 4; ++j)
            acc[i][j] = (floatx4){0.f, 0.f, 0.f, 0.f};

    for (int k0 = 0; k0 < K; k0 += BK) {
#pragma unroll
        for (int j = 0; j < 2; ++j) {
            __builtin_amdgcn_global_load_lds(
                (const __attribute__((address_space(1))) unsigned*)gA[j],
                (__attribute__((address_space(3))) unsigned*)lA[j], 16, 0, 0);
            __builtin_amdgcn_global_load_lds(
                (const __attribute__((address_space(1))) unsigned*)gB[j],
                (__attribute__((address_space(3))) unsigned*)lB[j], 16, 0, 0);
            gA[j] += BK * 2;   // advance 64 B along K
            gB[j] += BK * 2;
        }
        __syncthreads();   // compiler emits vmcnt(0) drain before s_barrier

        bf16x8 af[4], bfv[4];
#pragma unroll
        for (int i = 0; i < 4; ++i) { af[i] = aptr[i][0]; bfv[i] = bptr[i][0]; }
#pragma unroll
        for (int i = 0; i < 4; ++i)
#pragma unroll
            for (int j = 0; j < 4; ++j)
                acc[i][j] = __builtin_amdgcn_mfma_f32_16x16x32_bf16(
                    af[i], bfv[j], acc[i][j], 0, 0, 0);
        __syncthreads();
    }

    // Epilogue: D layout col=lane&15, row=(lane>>4)*4+reg  [m89/m91 verified]
#pragma unroll
    for (int tm = 0; tm < 4; ++tm)
#pragma unroll
        for (int tn = 0; tn < 4; ++tn) {
            int col = bn * BN + wn * 64 + tn * 16 + t;
#pragma unroll
            for (int r = 0; r < 4; ++r) {
                int rowg = bm * BM + wm * 64 + tm * 16 + q * 4 + r;
                C[(size_t)rowg * OUTD + col] = acc[tm][tn][r];
            }
        }
}

extern "C" void kernel_launch(void* const* d_in, const int* in_sizes, int n_in,
                              void* d_out, int out_size, void* d_ws, size_t ws_size,
                              hipStream_t stream) {
    const float* x    = (const float*)d_in[0];
    const float* coef = (const float*)d_in[1];
    const float* w    = (const float*)d_in[2];
    float* out = (float*)d_out;

    unsigned short* xb   = (unsigned short*)d_ws;                                  // 16 MB
    unsigned short* weff = (unsigned short*)((char*)d_ws + (size_t)BATCH * IN * 2); // +2 MB

    cvtx_kernel<<<(BATCH * IN / 8) / 256, 256, 0, stream>>>(x, xb);
    weff_kernel<<<(OUTD * IN / 2) / 256, 256, 0, stream>>>(coef, w, weff);
    gemm_bt<<<dim3(BATCH / 128, OUTD / 128), 256, 0, stream>>>(xb, weff, out);
}

// Round 2
// 125.736 us; speedup vs baseline: 1.0334x; 1.0334x over previous
//
#include <hip/hip_runtime.h>
#include <hip/hip_bf16.h>
#include <stdint.h>

#define BATCH 8192
#define IN    1024
#define OUTD  1024
#define PBASIS 8

typedef __attribute__((ext_vector_type(8))) short bf16x8;
typedef __attribute__((ext_vector_type(4))) float floatx4;

__device__ __forceinline__ unsigned short f2bf(float f) {
    union { float f; unsigned u; } v; v.f = f;
    unsigned u = v.u;
    u += 0x7fffu + ((u >> 16) & 1u);   // RNE; inputs finite randn
    return (unsigned short)(u >> 16);
}

// Fused prep: blocks [0,4096) convert x -> bf16 (8 elem/thread);
// blocks [4096,6144) compute w_eff = bf16(sum_p coef * w) (2 elem/thread).
__global__ void prep_kernel(const float* __restrict__ x,
                            const float* __restrict__ coef,
                            const float* __restrict__ w,
                            unsigned short* __restrict__ xb,
                            unsigned short* __restrict__ weff) {
    int b = blockIdx.x;
    int tid = threadIdx.x;
    if (b < 4096) {
        int idx = b * 256 + tid;
        const float4* p = (const float4*)(x + (size_t)idx * 8);
        float4 a = p[0], c = p[1];
        uint4 o;
        o.x = (unsigned)f2bf(a.x) | ((unsigned)f2bf(a.y) << 16);
        o.y = (unsigned)f2bf(a.z) | ((unsigned)f2bf(a.w) << 16);
        o.z = (unsigned)f2bf(c.x) | ((unsigned)f2bf(c.y) << 16);
        o.w = (unsigned)f2bf(c.z) | ((unsigned)f2bf(c.w) << 16);
        ((uint4*)xb)[idx] = o;
    } else {
        int idx = (b - 4096) * 256 + tid;   // element pair index
        size_t e0 = (size_t)idx * 2;
        const float4* c4 = (const float4*)(coef + e0 * PBASIS);
        float4 a = c4[0], bb = c4[1], c = c4[2], d = c4[3];
        float s0 = (a.x + a.y + a.z + a.w) + (bb.x + bb.y + bb.z + bb.w);
        float s1 = (c.x + c.y + c.z + c.w) + (d.x + d.y + d.z + d.w);
        float2 ww = ((const float2*)w)[idx];
        unsigned b0 = f2bf(s0 * ww.x);
        unsigned b1 = f2bf(s1 * ww.y);
        ((unsigned*)weff)[idx] = b0 | (b1 << 16);
    }
}

// C[m,n] = sum_k A[m,k]*B[n,k]; A=[8192,1024] bf16, B=[1024,1024] bf16, C f32.
// 128x128 tile, BK=64, 4 waves (2x2), wave does 4x4 of 16x16x32 MFMA, 2 K-halves.
// XOR swizzle (3-bit) on 16B chunks: staging keeps lane-contiguous LDS dest,
// fragment reads hit all 32 banks uniformly (conflict-free).
__global__ __launch_bounds__(256, 2) void gemm_bt(
        const unsigned short* __restrict__ A,
        const unsigned short* __restrict__ B,
        float* __restrict__ C) {
    constexpr int K = IN, BK = 64;
    constexpr int ES = 132;                       // epilogue stride (floats), pad vs 128
    __shared__ __align__(16) char smem[64 * ES * 4];   // 33792 B >= 32768 staging
    unsigned short* As = (unsigned short*)smem;        // 128 x 64 bf16 = 16 KB
    unsigned short* Bs = As + 128 * BK;                // 16 KB
    float* ebuf = (float*)smem;                        // epilogue reuse

    const int tid  = threadIdx.x;
    const int bm   = blockIdx.x, bn = blockIdx.y;
    const int lane = tid & 63;
    const int wave = tid >> 6;
    const int wm   = wave & 1, wn = wave >> 1;
    const int t    = lane & 15;    // M/N index within 16
    const int q    = lane >> 4;    // K-quad
    const int r8   = t & 7;        // swizzle key (row & 7, tile rows ≡ t mod 8)

    // ---- staging addresses: 4 chunks per matrix per thread ----
    const char* gA[4]; const char* gB[4];
    void* lA[4]; void* lB[4];
#pragma unroll
    for (int j = 0; j < 4; ++j) {
        int L = j * 256 + tid;       // 16B-chunk linear id, 1024 chunks per matrix
        int row = L >> 3;            // 8 chunks per 64-col row
        int cg  = (L & 7) ^ (row & 7);
        gA[j] = (const char*)(A + ((size_t)(bm * 128 + row)) * K + cg * 8);
        gB[j] = (const char*)(B + ((size_t)(bn * 128 + row)) * K + cg * 8);
        lA[j] = (void*)(As + (size_t)L * 8);
        lB[j] = (void*)(Bs + (size_t)L * 8);
    }

    // ---- fragment base pointers (imm-offset reads of i*1024 shorts) ----
    // A[m=wm*64+i*16+t][k=h*32+q*8+j] at phys chunk (h*4+q)^r8
    const unsigned short* aB0 = As + (wm * 64 + t) * BK + ((0 + q) ^ r8) * 8;
    const unsigned short* aB1 = As + (wm * 64 + t) * BK + ((4 + q) ^ r8) * 8;
    const unsigned short* bB0 = Bs + (wn * 64 + t) * BK + ((0 + q) ^ r8) * 8;
    const unsigned short* bB1 = Bs + (wn * 64 + t) * BK + ((4 + q) ^ r8) * 8;

    floatx4 acc[4][4];
#pragma unroll
    for (int i = 0; i < 4; ++i)
#pragma unroll
        for (int j = 0; j < 4; ++j)
            acc[i][j] = (floatx4){0.f, 0.f, 0.f, 0.f};

    for (int k0 = 0; k0 < K; k0 += BK) {
#pragma unroll
        for (int j = 0; j < 4; ++j) {
            __builtin_amdgcn_global_load_lds(
                (const __attribute__((address_space(1))) unsigned*)gA[j],
                (__attribute__((address_space(3))) unsigned*)lA[j], 16, 0, 0);
            __builtin_amdgcn_global_load_lds(
                (const __attribute__((address_space(1))) unsigned*)gB[j],
                (__attribute__((address_space(3))) unsigned*)lB[j], 16, 0, 0);
            gA[j] += BK * 2;   // 128 B along K
            gB[j] += BK * 2;
        }
        __syncthreads();

        bf16x8 af[2][4], bfv[2][4];
#pragma unroll
        for (int i = 0; i < 4; ++i) {
            af[0][i]  = *(const bf16x8*)(aB0 + i * 1024);
            af[1][i]  = *(const bf16x8*)(aB1 + i * 1024);
            bfv[0][i] = *(const bf16x8*)(bB0 + i * 1024);
            bfv[1][i] = *(const bf16x8*)(bB1 + i * 1024);
        }
#pragma unroll
        for (int i = 0; i < 4; ++i)
#pragma unroll
            for (int j = 0; j < 4; ++j) {
                acc[i][j] = __builtin_amdgcn_mfma_f32_16x16x32_bf16(
                    af[0][i], bfv[0][j], acc[i][j], 0, 0, 0);
                acc[i][j] = __builtin_amdgcn_mfma_f32_16x16x32_bf16(
                    af[1][i], bfv[1][j], acc[i][j], 0, 0, 0);
            }
        __syncthreads();
    }

    // ---- epilogue: LDS transpose -> coalesced float4 stores ----
    // D layout: col = t (lane&15), row = q*4 + reg  [m89/m91 verified]
#pragma unroll
    for (int p = 0; p < 2; ++p) {          // tm pairs {0,1}, {2,3}
        if (p) __syncthreads();            // protect ebuf reuse
#pragma unroll
        for (int dt = 0; dt < 2; ++dt) {
            int tm = 2 * p + dt;
#pragma unroll
            for (int tn = 0; tn < 4; ++tn) {
                int col = wn * 64 + tn * 16 + t;
#pragma unroll
                for (int r = 0; r < 4; ++r) {
                    int brow = wm * 32 + dt * 16 + q * 4 + r;
                    ebuf[brow * ES + col] = acc[tm][tn][r];
                }
            }
        }
        __syncthreads();
#pragma unroll
        for (int rr = 0; rr < 8; ++rr) {
            int brow = rr * 8 + (tid >> 5);
            int col4 = tid & 31;
            float4 v = *(const float4*)(ebuf + brow * ES + col4 * 4);
            int lrow = brow + ((brow >> 5) << 5) + p * 32;   // wm*64 + p*32 + u
            size_t off = ((size_t)(bm * 128 + lrow) * OUTD + bn * 128 + col4 * 4);
            *(float4*)(C + off) = v;
        }
    }
}

extern "C" void kernel_launch(void* const* d_in, const int* in_sizes, int n_in,
                              void* d_out, int out_size, void* d_ws, size_t ws_size,
                              hipStream_t stream) {
    const float* x    = (const float*)d_in[0];
    const float* coef = (const float*)d_in[1];
    const float* w    = (const float*)d_in[2];
    float* out = (float*)d_out;

    unsigned short* xb   = (unsigned short*)d_ws;                                   // 16 MB
    unsigned short* weff = (unsigned short*)((char*)d_ws + (size_t)BATCH * IN * 2); // +2 MB

    prep_kernel<<<6144, 256, 0, stream>>>(x, coef, w, xb, weff);
    gemm_bt<<<dim3(BATCH / 128, OUTD / 128), 256, 0, stream>>>(xb, weff, out);
}

// Round 3
// 125.597 us; speedup vs baseline: 1.0345x; 1.0011x over previous
//
#include <hip/hip_runtime.h>
#include <hip/hip_bf16.h>
#include <stdint.h>

#define BATCH 8192
#define IN    1024
#define OUTD  1024
#define PBASIS 8

typedef __attribute__((ext_vector_type(8))) short bf16x8;
typedef __attribute__((ext_vector_type(4))) float floatx4;

__device__ __forceinline__ unsigned short f2bf(float f) {
    union { float f; unsigned u; } v; v.f = f;
    unsigned u = v.u;
    u += 0x7fffu + ((u >> 16) & 1u);   // RNE; inputs finite randn
    return (unsigned short)(u >> 16);
}

// Fused prep: blocks [0,4096) convert x -> bf16 (8 elem/thread);
// blocks [4096,6144) compute w_eff = bf16(sum_p coef * w) (2 elem/thread).
__global__ void prep_kernel(const float* __restrict__ x,
                            const float* __restrict__ coef,
                            const float* __restrict__ w,
                            unsigned short* __restrict__ xb,
                            unsigned short* __restrict__ weff) {
    int b = blockIdx.x;
    int tid = threadIdx.x;
    if (b < 4096) {
        int idx = b * 256 + tid;
        const float4* p = (const float4*)(x + (size_t)idx * 8);
        float4 a = p[0], c = p[1];
        uint4 o;
        o.x = (unsigned)f2bf(a.x) | ((unsigned)f2bf(a.y) << 16);
        o.y = (unsigned)f2bf(a.z) | ((unsigned)f2bf(a.w) << 16);
        o.z = (unsigned)f2bf(c.x) | ((unsigned)f2bf(c.y) << 16);
        o.w = (unsigned)f2bf(c.z) | ((unsigned)f2bf(c.w) << 16);
        ((uint4*)xb)[idx] = o;
    } else {
        int idx = (b - 4096) * 256 + tid;   // element pair index
        size_t e0 = (size_t)idx * 2;
        const float4* c4 = (const float4*)(coef + e0 * PBASIS);
        float4 a = c4[0], bb = c4[1], c = c4[2], d = c4[3];
        float s0 = (a.x + a.y + a.z + a.w) + (bb.x + bb.y + bb.z + bb.w);
        float s1 = (c.x + c.y + c.z + c.w) + (d.x + d.y + d.z + d.w);
        float2 ww = ((const float2*)w)[idx];
        unsigned b0 = f2bf(s0 * ww.x);
        unsigned b1 = f2bf(s1 * ww.y);
        ((unsigned*)weff)[idx] = b0 | (b1 << 16);
    }
}

// C[m,n] = sum_k A[m,k]*B[n,k]; A=[8192,1024] bf16, B=[1024,1024] bf16, C f32.
// 128x128 tile, BK=64, 4 waves (2x2), wave does 4x4 of 16x16x32 MFMA.
// LDS exactly 32 KB (staging; epilogue reuses it in 32-row passes) and
// __launch_bounds__(256,3) -> <=168 VGPR -> 3 blocks/CU for drain hiding.
__global__ __launch_bounds__(256, 3) void gemm_bt(
        const unsigned short* __restrict__ A,
        const unsigned short* __restrict__ B,
        float* __restrict__ C) {
    constexpr int K = IN, BK = 64;
    constexpr int ES = 132;                        // epilogue row stride (floats)
    __shared__ __align__(16) char smem[32768];     // staging 32 KB; ebuf 32*132*4=16.9 KB
    unsigned short* As = (unsigned short*)smem;    // 128 x 64 bf16 = 16 KB
    unsigned short* Bs = As + 128 * BK;            // 16 KB
    float* ebuf = (float*)smem;                    // epilogue reuse

    const int tid  = threadIdx.x;
    const int bm   = blockIdx.x, bn = blockIdx.y;
    const int lane = tid & 63;
    const int wave = tid >> 6;
    const int wm   = wave & 1, wn = wave >> 1;
    const int t    = lane & 15;    // M/N index within 16
    const int q    = lane >> 4;    // K-quad
    const int r8   = t & 7;        // XOR swizzle key

    // ---- staging addresses: 4 chunks per matrix per thread ----
    const char* gA[4]; const char* gB[4];
    void* lA[4]; void* lB[4];
#pragma unroll
    for (int j = 0; j < 4; ++j) {
        int L = j * 256 + tid;       // 16B-chunk linear id
        int row = L >> 3;            // 8 chunks per 64-col row
        int cg  = (L & 7) ^ (row & 7);
        gA[j] = (const char*)(A + ((size_t)(bm * 128 + row)) * K + cg * 8);
        gB[j] = (const char*)(B + ((size_t)(bn * 128 + row)) * K + cg * 8);
        lA[j] = (void*)(As + (size_t)L * 8);
        lB[j] = (void*)(Bs + (size_t)L * 8);
    }

    // ---- fragment base pointers ----
    const unsigned short* aB0 = As + (wm * 64 + t) * BK + ((0 + q) ^ r8) * 8;
    const unsigned short* aB1 = As + (wm * 64 + t) * BK + ((4 + q) ^ r8) * 8;
    const unsigned short* bB0 = Bs + (wn * 64 + t) * BK + ((0 + q) ^ r8) * 8;
    const unsigned short* bB1 = Bs + (wn * 64 + t) * BK + ((4 + q) ^ r8) * 8;

    floatx4 acc[4][4];
#pragma unroll
    for (int i = 0; i < 4; ++i)
#pragma unroll
        for (int j = 0; j < 4; ++j)
            acc[i][j] = (floatx4){0.f, 0.f, 0.f, 0.f};

    for (int k0 = 0; k0 < K; k0 += BK) {
#pragma unroll
        for (int j = 0; j < 4; ++j) {
            __builtin_amdgcn_global_load_lds(
                (const __attribute__((address_space(1))) unsigned*)gA[j],
                (__attribute__((address_space(3))) unsigned*)lA[j], 16, 0, 0);
            __builtin_amdgcn_global_load_lds(
                (const __attribute__((address_space(1))) unsigned*)gB[j],
                (__attribute__((address_space(3))) unsigned*)lB[j], 16, 0, 0);
            gA[j] += BK * 2;   // 128 B along K
            gB[j] += BK * 2;
        }
        __syncthreads();

        bf16x8 af[2][4], bfv[2][4];
#pragma unroll
        for (int i = 0; i < 4; ++i) {
            af[0][i]  = *(const bf16x8*)(aB0 + i * 1024);
            af[1][i]  = *(const bf16x8*)(aB1 + i * 1024);
            bfv[0][i] = *(const bf16x8*)(bB0 + i * 1024);
            bfv[1][i] = *(const bf16x8*)(bB1 + i * 1024);
        }
#pragma unroll
        for (int i = 0; i < 4; ++i)
#pragma unroll
            for (int j = 0; j < 4; ++j) {
                acc[i][j] = __builtin_amdgcn_mfma_f32_16x16x32_bf16(
                    af[0][i], bfv[0][j], acc[i][j], 0, 0, 0);
                acc[i][j] = __builtin_amdgcn_mfma_f32_16x16x32_bf16(
                    af[1][i], bfv[1][j], acc[i][j], 0, 0, 0);
            }
        __syncthreads();
    }

    // ---- epilogue: 4 passes of 32 rows through 16.9 KB ebuf ----
    // D layout: col = t (lane&15), row = q*4 + reg  [m89/m91 verified]
#pragma unroll
    for (int p = 0; p < 4; ++p) {          // block rows [p*32, p*32+32)
        if (p) __syncthreads();            // protect ebuf reuse across passes
        if (wm == (p >> 1)) {
            int dt = p & 1;
#pragma unroll
            for (int half = 0; half < 2; ++half) {
                int tm = dt * 2 + half;
#pragma unroll
                for (int tn = 0; tn < 4; ++tn) {
                    int col = wn * 64 + tn * 16 + t;
#pragma unroll
                    for (int r = 0; r < 4; ++r) {
                        int brow = half * 16 + q * 4 + r;
                        ebuf[brow * ES + col] = acc[tm][tn][r];
                    }
                }
            }
        }
        __syncthreads();
#pragma unroll
        for (int rr = 0; rr < 4; ++rr) {
            int brow = rr * 8 + (tid >> 5);
            int col4 = tid & 31;
            float4 v = *(const float4*)(ebuf + brow * ES + col4 * 4);
            size_t grow = (size_t)(bm * 128 + p * 32 + brow);
            *(float4*)(C + grow * OUTD + bn * 128 + col4 * 4) = v;
        }
    }
}

extern "C" void kernel_launch(void* const* d_in, const int* in_sizes, int n_in,
                              void* d_out, int out_size, void* d_ws, size_t ws_size,
                              hipStream_t stream) {
    const float* x    = (const float*)d_in[0];
    const float* coef = (const float*)d_in[1];
    const float* w    = (const float*)d_in[2];
    float* out = (float*)d_out;

    unsigned short* xb   = (unsigned short*)d_ws;                                   // 16 MB
    unsigned short* weff = (unsigned short*)((char*)d_ws + (size_t)BATCH * IN * 2); // +2 MB

    prep_kernel<<<6144, 256, 0, stream>>>(x, coef, w, xb, weff);
    gemm_bt<<<dim3(BATCH / 128, OUTD / 128), 256, 0, stream>>>(xb, weff, out);
}